// Round 7
// baseline (130.531 us; speedup 1.0000x reference)
//
#include <hip/hip_runtime.h>

// Problem geometry: B=64, A=9, H=W=128, C=1000
// N4 = 64*9*4096 = 2,359,296 float4 units over (B,A,H,W).
// Plane = 4096 float4. chunk = 128 float4 (2 KB per plane per round).
// Grid: 2304 blocks x 8 rounds x 128 f4 = exact cover.
// Block b: plane ba = b>>2, sub-range sub = b&3 (1024 f4), rounds walk it.
// 128 threads = 2 waves; each wave stages and reads ONLY its own 64-lane
// slice of each plane => waves are independent, NO barriers in the loop.
static constexpr int HW4   = 4096;
static constexpr int CHUNK = 128;
static constexpr int ROUNDS = 8;
static constexpr float LOGCLAMP = -100.0f;

// ws layout: ws[0]=no_obj_confi, ws[1]=obj_confi, ws[2]=obj_coor, ws[3]=img_class

// Async HBM->LDS, 16 B per lane; zero data-VGPR cost; counted by vmcnt.
// LDS dest = wave-uniform base + lane*16; global src is per-lane.
__device__ __forceinline__ void stage16(const float4* g, float4* l) {
    __builtin_amdgcn_global_load_lds(
        (const __attribute__((address_space(1))) void*)g,
        (__attribute__((address_space(3))) void*)l,
        16, 0, 0);
}

__global__ __launch_bounds__(128) void main_loss_kernel(
    const float4* __restrict__ objects,   // (576, 4096)
    const float4* __restrict__ locs,      // (576, 4, 4096)
    const float4* __restrict__ gt,        // (576, 5, 4096)
    float* __restrict__ ws)
{
    // 2 buffers x 10 planes x 128 float4 = 40 KB
    __shared__ float4 lds[2][10][CHUNK];

    const int b   = blockIdx.x;
    const int tid = threadIdx.x;          // 0..127
    const int wb  = tid & ~63;            // wave's slice base (0 or 64)

    const int ba  = b >> 2;               // plane index (0..575)
    const int sub = b & 3;                 // which 1024-f4 quarter of the plane

    const float4* pO  = objects + ba * HW4     + sub * 1024;
    const float4* gtb = gt      + ba * 5 * HW4 + sub * 1024;
    const float4* lcb = locs    + ba * 4 * HW4 + sub * 1024;

    // Issue one round's 10 plane-loads (10 x 1 KB per wave in flight).
    auto stage_round = [&](int r) {
        const int off = r * CHUNK + tid;
        float4* dst = &lds[r & 1][0][wb];
        stage16(pO  + off,            dst + 0 * CHUNK);   // objects
        stage16(gtb + 0 * HW4 + off,  dst + 1 * CHUNK);   // m
        stage16(gtb + 1 * HW4 + off,  dst + 2 * CHUNK);   // gt coords
        stage16(gtb + 2 * HW4 + off,  dst + 3 * CHUNK);
        stage16(gtb + 3 * HW4 + off,  dst + 4 * CHUNK);
        stage16(gtb + 4 * HW4 + off,  dst + 5 * CHUNK);
        stage16(lcb + 0 * HW4 + off,  dst + 6 * CHUNK);   // locs coords
        stage16(lcb + 1 * HW4 + off,  dst + 7 * CHUNK);
        stage16(lcb + 2 * HW4 + off,  dst + 8 * CHUNK);
        stage16(lcb + 3 * HW4 + off,  dst + 9 * CHUNK);
    };

    float s_noobj = 0.0f, s_obj = 0.0f, s_coor = 0.0f;

    // ---- prologue: 2 rounds in flight (20 loads/wave) ----
    stage_round(0);
    stage_round(1);

    #pragma unroll
    for (int r = 0; r < ROUNDS; ++r) {
        // Round r's 10 loads are the oldest 10 outstanding.
        if (r < ROUNDS - 1)
            asm volatile("s_waitcnt vmcnt(10)" ::: "memory");
        else
            asm volatile("s_waitcnt vmcnt(0)" ::: "memory");
        __builtin_amdgcn_sched_barrier(0);

        // Read this wave's slice (contiguous ds_read_b128, conflict-free).
        const int buf = r & 1;
        const float4 o  = lds[buf][0][tid];
        const float4 m  = lds[buf][1][tid];
        const float4 g0 = lds[buf][2][tid];
        const float4 g1 = lds[buf][3][tid];
        const float4 g2 = lds[buf][4][tid];
        const float4 g3 = lds[buf][5][tid];
        const float4 l0 = lds[buf][6][tid];
        const float4 l1 = lds[buf][7][tid];
        const float4 l2 = lds[buf][8][tid];
        const float4 l3 = lds[buf][9][tid];

        if (r < ROUNDS - 2) {
            // Buffer free once our ds_reads retired; restage it (round r+2)
            // so 20 loads stay in flight. Waits LDS pipe only, not HBM.
            asm volatile("s_waitcnt lgkmcnt(0)" ::: "memory");
            __builtin_amdgcn_sched_barrier(0);
            stage_round(r + 2);
        }

        {
            const float d0 = l0.x - g0.x, d1 = l1.x - g1.x,
                        d2 = l2.x - g2.x, d3 = l3.x - g3.x;
            const float sq = d0 * d0 + d1 * d1 + d2 * d2 + d3 * d3;
            const float lp  = fmaxf(__logf(o.x),        LOGCLAMP);
            const float l1m = fmaxf(__logf(1.0f - o.x), LOGCLAMP);
            s_noobj -= (1.0f - m.x) * l1m;
            s_obj   -= m.x * lp;
            s_coor  += m.x * sq;
        }
        {
            const float d0 = l0.y - g0.y, d1 = l1.y - g1.y,
                        d2 = l2.y - g2.y, d3 = l3.y - g3.y;
            const float sq = d0 * d0 + d1 * d1 + d2 * d2 + d3 * d3;
            const float lp  = fmaxf(__logf(o.y),        LOGCLAMP);
            const float l1m = fmaxf(__logf(1.0f - o.y), LOGCLAMP);
            s_noobj -= (1.0f - m.y) * l1m;
            s_obj   -= m.y * lp;
            s_coor  += m.y * sq;
        }
        {
            const float d0 = l0.z - g0.z, d1 = l1.z - g1.z,
                        d2 = l2.z - g2.z, d3 = l3.z - g3.z;
            const float sq = d0 * d0 + d1 * d1 + d2 * d2 + d3 * d3;
            const float lp  = fmaxf(__logf(o.z),        LOGCLAMP);
            const float l1m = fmaxf(__logf(1.0f - o.z), LOGCLAMP);
            s_noobj -= (1.0f - m.z) * l1m;
            s_obj   -= m.z * lp;
            s_coor  += m.z * sq;
        }
        {
            const float d0 = l0.w - g0.w, d1 = l1.w - g1.w,
                        d2 = l2.w - g2.w, d3 = l3.w - g3.w;
            const float sq = d0 * d0 + d1 * d1 + d2 * d2 + d3 * d3;
            const float lp  = fmaxf(__logf(o.w),        LOGCLAMP);
            const float l1m = fmaxf(__logf(1.0f - o.w), LOGCLAMP);
            s_noobj -= (1.0f - m.w) * l1m;
            s_obj   -= m.w * lp;
            s_coor  += m.w * sq;
        }
    }

    // wave64 reduce all three sums
    #pragma unroll
    for (int off = 32; off > 0; off >>= 1) {
        s_noobj += __shfl_down(s_noobj, off, 64);
        s_obj   += __shfl_down(s_obj,   off, 64);
        s_coor  += __shfl_down(s_coor,  off, 64);
    }

    __shared__ float red[3][2];
    const int lane = tid & 63;
    const int wid  = tid >> 6;
    if (lane == 0) {
        red[0][wid] = s_noobj;
        red[1][wid] = s_obj;
        red[2][wid] = s_coor;
    }
    __syncthreads();
    if (tid == 0) {
        atomicAdd(&ws[0], red[0][0] + red[0][1]);
        atomicAdd(&ws[1], red[1][0] + red[1][1]);
        atomicAdd(&ws[2], red[2][0] + red[2][1]);
    }
}

// img_class_loss: one block per batch row, C=1000
__global__ __launch_bounds__(256) void class_loss_kernel(
    const float* __restrict__ scores,   // (64, 1000)
    const int*   __restrict__ label,    // (64,)
    float* __restrict__ ws)
{
    const int b = blockIdx.x;
    const float* row = scores + b * 1000;

    float mx = -INFINITY;
    for (int i = threadIdx.x; i < 1000; i += 256) mx = fmaxf(mx, row[i]);
    #pragma unroll
    for (int off = 32; off > 0; off >>= 1) mx = fmaxf(mx, __shfl_down(mx, off, 64));

    __shared__ float smax[4];
    const int lane = threadIdx.x & 63;
    const int wid  = threadIdx.x >> 6;
    if (lane == 0) smax[wid] = mx;
    __syncthreads();
    mx = fmaxf(fmaxf(smax[0], smax[1]), fmaxf(smax[2], smax[3]));

    float se = 0.0f;
    for (int i = threadIdx.x; i < 1000; i += 256) se += __expf(row[i] - mx);
    #pragma unroll
    for (int off = 32; off > 0; off >>= 1) se += __shfl_down(se, off, 64);

    __shared__ float ssum[4];
    if (lane == 0) ssum[wid] = se;
    __syncthreads();
    if (threadIdx.x == 0) {
        se = ssum[0] + ssum[1] + ssum[2] + ssum[3];
        const float logp = row[label[b]] - mx - __logf(se);
        atomicAdd(&ws[3], -logp * (1.0f / 64.0f));   // mean over B
    }
}

__global__ void finalize_kernel(const float* __restrict__ ws, float* __restrict__ out)
{
    // IMG_CLASS_WEIGHT*class + (0.5*noobj + 1.0*obj + 5.0*coor)/B
    out[0] = ws[3] + (0.5f * ws[0] + 1.0f * ws[1] + 5.0f * ws[2]) * (1.0f / 64.0f);
}

extern "C" void kernel_launch(void* const* d_in, const int* in_sizes, int n_in,
                              void* d_out, int out_size, void* d_ws, size_t ws_size,
                              hipStream_t stream)
{
    const float* objects = (const float*)d_in[0];   // (64,9,128,128)
    const float* scores  = (const float*)d_in[1];   // (64,1000)
    const float* locs    = (const float*)d_in[2];   // (64,9,4,128,128)
    const int*   label   = (const int*)d_in[3];     // (64,)
    const float* gt      = (const float*)d_in[4];   // (64,9,5,128,128)
    float* ws  = (float*)d_ws;
    float* out = (float*)d_out;

    hipMemsetAsync(ws, 0, 4 * sizeof(float), stream);

    main_loss_kernel<<<2304, 128, 0, stream>>>(
        (const float4*)objects, (const float4*)locs, (const float4*)gt, ws);
    class_loss_kernel<<<64, 256, 0, stream>>>(scores, label, ws);
    finalize_kernel<<<1, 1, 0, stream>>>(ws, out);
}

// Round 9
// 120.983 us; speedup vs baseline: 1.0789x; 1.0789x over previous
//
#include <hip/hip_runtime.h>

// Problem geometry: B=64, A=9, H=W=128, C=1000
// N4 = 64*9*4096 = 2,359,296 float4 units over (B,A,H,W).
// Plane = 4096 float4. Block b: plane ba = b>>2, quarter sub = b&3
// (1024 f4 per plane). 4 rounds x CHUNK=256 f4 = exact cover.
// 2304 blocks x 256 threads.
//
// Cache partition (round-8 experiment):
//   locs (151 MB)        -> __builtin_nontemporal_load (nt: no L2/L3
//                           allocate) - streams from HBM, VGPR path.
//   objects+gt (226 MB)  -> global_load_lds staged, normal caching;
//                           fits in 256 MB L3 -> resident across replays.
// Each wave stages and reads ONLY its own 64-lane LDS slice => no barriers.
static constexpr int HW4    = 4096;
static constexpr int CHUNK  = 256;
static constexpr int ROUNDS = 4;
static constexpr float LOGCLAMP = -100.0f;

typedef float v4f __attribute__((ext_vector_type(4)));

// ws layout: ws[0]=no_obj_confi, ws[1]=obj_confi, ws[2]=obj_coor, ws[3]=img_class

// Async HBM->LDS, 16 B per lane; zero data-VGPR cost; counted by vmcnt.
__device__ __forceinline__ void stage16(const float4* g, float4* l) {
    __builtin_amdgcn_global_load_lds(
        (const __attribute__((address_space(1))) void*)g,
        (__attribute__((address_space(3))) void*)l,
        16, 0, 0);
}

__global__ __launch_bounds__(256) void main_loss_kernel(
    const float4* __restrict__ objects,   // (576, 4096)
    const float4* __restrict__ locs,      // (576, 4, 4096)
    const float4* __restrict__ gt,        // (576, 5, 4096)
    float* __restrict__ ws)
{
    // 6 staged planes x 256 float4 = 24 KB: o, m, g0..g3
    __shared__ float4 lds[6][CHUNK];

    const int b   = blockIdx.x;
    const int tid = threadIdx.x;          // 0..255
    const int wb  = tid & ~63;            // wave's slice base

    const int ba  = b >> 2;               // plane index (0..575)
    const int sub = b & 3;                 // quarter of the plane

    const float4* pO  = objects + ba * HW4     + sub * 1024;
    const float4* gtb = gt      + ba * 5 * HW4 + sub * 1024;
    const v4f*    lcb = (const v4f*)(locs + ba * 4 * HW4 + sub * 1024);

    float s_noobj = 0.0f, s_obj = 0.0f, s_coor = 0.0f;

    #pragma unroll 1
    for (int r = 0; r < ROUNDS; ++r) {
        const int off = r * CHUNK + tid;

        // ---- nt loads of locs (VGPR path, HBM stream, no cache alloc) ----
        const v4f L0 = __builtin_nontemporal_load(lcb + 0 * HW4 + off);
        const v4f L1 = __builtin_nontemporal_load(lcb + 1 * HW4 + off);
        const v4f L2 = __builtin_nontemporal_load(lcb + 2 * HW4 + off);
        const v4f L3 = __builtin_nontemporal_load(lcb + 3 * HW4 + off);

        // ---- staged (cached) path: objects + gt, 6 planes ----
        stage16(pO  + off,           &lds[0][wb]);
        stage16(gtb + 0 * HW4 + off, &lds[1][wb]);
        stage16(gtb + 1 * HW4 + off, &lds[2][wb]);
        stage16(gtb + 2 * HW4 + off, &lds[3][wb]);
        stage16(gtb + 3 * HW4 + off, &lds[4][wb]);
        stage16(gtb + 4 * HW4 + off, &lds[5][wb]);

        // All 10 streams of this round are now in flight together.
        asm volatile("s_waitcnt vmcnt(0)" ::: "memory");
        __builtin_amdgcn_sched_barrier(0);

        // Own-slice LDS reads (contiguous ds_read_b128, conflict-free).
        const float4 o  = lds[0][tid];
        const float4 m  = lds[1][tid];
        const float4 g0 = lds[2][tid];
        const float4 g1 = lds[3][tid];
        const float4 g2 = lds[4][tid];
        const float4 g3 = lds[5][tid];

        {
            const float d0 = L0[0] - g0.x, d1 = L1[0] - g1.x,
                        d2 = L2[0] - g2.x, d3 = L3[0] - g3.x;
            const float sq = d0 * d0 + d1 * d1 + d2 * d2 + d3 * d3;
            const float lp  = fmaxf(__logf(o.x),        LOGCLAMP);
            const float l1m = fmaxf(__logf(1.0f - o.x), LOGCLAMP);
            s_noobj -= (1.0f - m.x) * l1m;
            s_obj   -= m.x * lp;
            s_coor  += m.x * sq;
        }
        {
            const float d0 = L0[1] - g0.y, d1 = L1[1] - g1.y,
                        d2 = L2[1] - g2.y, d3 = L3[1] - g3.y;
            const float sq = d0 * d0 + d1 * d1 + d2 * d2 + d3 * d3;
            const float lp  = fmaxf(__logf(o.y),        LOGCLAMP);
            const float l1m = fmaxf(__logf(1.0f - o.y), LOGCLAMP);
            s_noobj -= (1.0f - m.y) * l1m;
            s_obj   -= m.y * lp;
            s_coor  += m.y * sq;
        }
        {
            const float d0 = L0[2] - g0.z, d1 = L1[2] - g1.z,
                        d2 = L2[2] - g2.z, d3 = L3[2] - g3.z;
            const float sq = d0 * d0 + d1 * d1 + d2 * d2 + d3 * d3;
            const float lp  = fmaxf(__logf(o.z),        LOGCLAMP);
            const float l1m = fmaxf(__logf(1.0f - o.z), LOGCLAMP);
            s_noobj -= (1.0f - m.z) * l1m;
            s_obj   -= m.z * lp;
            s_coor  += m.z * sq;
        }
        {
            const float d0 = L0[3] - g0.w, d1 = L1[3] - g1.w,
                        d2 = L2[3] - g2.w, d3 = L3[3] - g3.w;
            const float sq = d0 * d0 + d1 * d1 + d2 * d2 + d3 * d3;
            const float lp  = fmaxf(__logf(o.w),        LOGCLAMP);
            const float l1m = fmaxf(__logf(1.0f - o.w), LOGCLAMP);
            s_noobj -= (1.0f - m.w) * l1m;
            s_obj   -= m.w * lp;
            s_coor  += m.w * sq;
        }
    }

    // wave64 reduce all three sums
    #pragma unroll
    for (int off = 32; off > 0; off >>= 1) {
        s_noobj += __shfl_down(s_noobj, off, 64);
        s_obj   += __shfl_down(s_obj,   off, 64);
        s_coor  += __shfl_down(s_coor,  off, 64);
    }

    __shared__ float red[3][4];
    const int lane = tid & 63;
    const int wid  = tid >> 6;
    if (lane == 0) {
        red[0][wid] = s_noobj;
        red[1][wid] = s_obj;
        red[2][wid] = s_coor;
    }
    __syncthreads();
    if (tid == 0) {
        atomicAdd(&ws[0], red[0][0] + red[0][1] + red[0][2] + red[0][3]);
        atomicAdd(&ws[1], red[1][0] + red[1][1] + red[1][2] + red[1][3]);
        atomicAdd(&ws[2], red[2][0] + red[2][1] + red[2][2] + red[2][3]);
    }
}

// img_class_loss: one block per batch row, C=1000
__global__ __launch_bounds__(256) void class_loss_kernel(
    const float* __restrict__ scores,   // (64, 1000)
    const int*   __restrict__ label,    // (64,)
    float* __restrict__ ws)
{
    const int b = blockIdx.x;
    const float* row = scores + b * 1000;

    float mx = -INFINITY;
    for (int i = threadIdx.x; i < 1000; i += 256) mx = fmaxf(mx, row[i]);
    #pragma unroll
    for (int off = 32; off > 0; off >>= 1) mx = fmaxf(mx, __shfl_down(mx, off, 64));

    __shared__ float smax[4];
    const int lane = threadIdx.x & 63;
    const int wid  = threadIdx.x >> 6;
    if (lane == 0) smax[wid] = mx;
    __syncthreads();
    mx = fmaxf(fmaxf(smax[0], smax[1]), fmaxf(smax[2], smax[3]));

    float se = 0.0f;
    for (int i = threadIdx.x; i < 1000; i += 256) se += __expf(row[i] - mx);
    #pragma unroll
    for (int off = 32; off > 0; off >>= 1) se += __shfl_down(se, off, 64);

    __shared__ float ssum[4];
    if (lane == 0) ssum[wid] = se;
    __syncthreads();
    if (threadIdx.x == 0) {
        se = ssum[0] + ssum[1] + ssum[2] + ssum[3];
        const float logp = row[label[b]] - mx - __logf(se);
        atomicAdd(&ws[3], -logp * (1.0f / 64.0f));   // mean over B
    }
}

__global__ void finalize_kernel(const float* __restrict__ ws, float* __restrict__ out)
{
    // IMG_CLASS_WEIGHT*class + (0.5*noobj + 1.0*obj + 5.0*coor)/B
    out[0] = ws[3] + (0.5f * ws[0] + 1.0f * ws[1] + 5.0f * ws[2]) * (1.0f / 64.0f);
}

extern "C" void kernel_launch(void* const* d_in, const int* in_sizes, int n_in,
                              void* d_out, int out_size, void* d_ws, size_t ws_size,
                              hipStream_t stream)
{
    const float* objects = (const float*)d_in[0];   // (64,9,128,128)
    const float* scores  = (const float*)d_in[1];   // (64,1000)
    const float* locs    = (const float*)d_in[2];   // (64,9,4,128,128)
    const int*   label   = (const int*)d_in[3];     // (64,)
    const float* gt      = (const float*)d_in[4];   // (64,9,5,128,128)
    float* ws  = (float*)d_ws;
    float* out = (float*)d_out;

    hipMemsetAsync(ws, 0, 4 * sizeof(float), stream);

    main_loss_kernel<<<2304, 256, 0, stream>>>(
        (const float4*)objects, (const float4*)locs, (const float4*)gt, ws);
    class_loss_kernel<<<64, 256, 0, stream>>>(scores, label, ws);
    finalize_kernel<<<1, 1, 0, stream>>>(ws, out);
}